// Round 6
// baseline (152.153 us; speedup 1.0000x reference)
//
#include <hip/hip_runtime.h>

#define NL  4096
#define TPB 512

typedef float v2f __attribute__((ext_vector_type(2)));

__device__ __forceinline__ float rfl(float x) {
    return __uint_as_float(__builtin_amdgcn_readfirstlane(__float_as_uint(x)));
}
__device__ __forceinline__ float fast_rcp(float x) { return __builtin_amdgcn_rcpf(x); }
__device__ __forceinline__ float fexp2(float x) { return __builtin_amdgcn_exp2f(x); }  // 2^x
__device__ __forceinline__ float flog2(float x) { return __builtin_amdgcn_logf(x); }   // log2(x)

#define L2E 1.44269504088896340736f
#define LN2 0.69314718055994530942f

// One block per battery row; 512 threads; thread t owns steps [4t..4t+3] (phase A)
// and [2048+4t..2048+4t+3] (phase B). Each phase: coalesced global->LDS stage
// (linear copy; 20-word records give conflict-free b128 reads), then per-thread
// affine composition on (U,S): U'=a*U+b ; S'=S+(1/I)*U. theta linearized:
//   theta_k = AL_k + sum_j log2(1+2^pre_j) * V[j,k]
__global__ void __launch_bounds__(TPB) onenet_fused(
    const float* __restrict__ X,   const float* __restrict__ SC,
    const float* __restrict__ pW1, const float* __restrict__ pb1,
    const float* __restrict__ pW2, const float* __restrict__ pb2,
    const float* __restrict__ rW1, const float* __restrict__ rb1,
    const float* __restrict__ rW2, const float* __restrict__ rb2,
    float* __restrict__ out)
{
    __shared__ float buf[TPB * 20];        // 40 KB staging; red[] aliases it later
    float* red = buf;                      // 8 waves x 17 floats, words 0..135

    const int row  = blockIdx.x;
    const int tid  = threadIdx.x;
    const int lane = tid & 63;
    const int w    = tid >> 6;

    // ---- uniform weight prologue (per block; amortized over 4096 steps) ----
    const float LBv[5]  = {0.005f, 0.025f, 0.1f, 0.0f, 0.002f};
    const float UBLB[5] = {0.015f, 0.045f, 0.9f, 0.055f, 0.023f};

    float sc0 = rfl(SC[row * 3 + 0]);
    float sc1 = rfl(SC[row * 3 + 1]);
    float sc2 = rfl(SC[row * 3 + 2]);

    float W1S[10], W1T[10], BASE[10], V4[10];
    v2f V01[10], V23[10], AL01, AL23;
    float AL4;
#pragma unroll
    for (int j = 0; j < 10; ++j) {
        W1S[j]  = rfl(L2E * pW1[j]);
        W1T[j]  = rfl(L2E * pW1[10 + j]);
        BASE[j] = rfl(L2E * fmaf(sc0, pW1[20 + j],
                            fmaf(sc1, pW1[30 + j],
                            fmaf(sc2, pW1[40 + j], pb1[j]))));
        V01[j].x = rfl(LN2 * 0.0025f * UBLB[0] * pW2[5 * j + 0]);
        V01[j].y = rfl(LN2 * 0.0025f * UBLB[1] * pW2[5 * j + 1]);
        V23[j].x = rfl(LN2 * 0.0025f * UBLB[2] * pW2[5 * j + 2]);
        V23[j].y = rfl(LN2 * 0.0025f * UBLB[3] * pW2[5 * j + 3]);
        V4[j]    = rfl(LN2 * 0.0025f * UBLB[4] * pW2[5 * j + 4]);
    }
    AL01.x = rfl(LBv[0] + UBLB[0] * fmaf(0.0025f, pb2[0], 0.5f));
    AL01.y = rfl(LBv[1] + UBLB[1] * fmaf(0.0025f, pb2[1], 0.5f));
    AL23.x = rfl(LBv[2] + UBLB[2] * fmaf(0.0025f, pb2[2], 0.5f));
    AL23.y = rfl(LBv[3] + UBLB[3] * fmaf(0.0025f, pb2[3], 0.5f));
    AL4    = rfl(LBv[4] + UBLB[4] * fmaf(0.0025f, pb2[4], 0.5f));

    const float* Xrow = X + (size_t)row * NL * 5;
    float4* bq = (float4*)buf;

    v2f aA, bA, cA, dA;                    // phase-A composition results
    v2f a = {1.f, 1.f}, b = {0.f, 0.f}, cS = {0.f, 0.f}, dS = {0.f, 0.f};
    float oacc = 0.f, OCV0 = 0.f, I0 = 0.f, SOC0 = 0.f, T0 = 0.f;
    float f[20];

    // ================= phase A: steps [0..2047] =================
    {
        const float4* gq = (const float4*)Xrow;
#pragma unroll
        for (int k = 0; k < 5; ++k) bq[tid + TPB * k] = gq[tid + TPB * k];
    }
    __syncthreads();                                   // stage A visible
#pragma unroll
    for (int j = 0; j < 5; ++j)
        *(float4*)&f[4 * j] = bq[5 * tid + j];
    float tnl = buf[20 * ((tid + 1) & (TPB - 1))];
    float tnA = (tid == TPB - 1) ? Xrow[10240] : tnl;  // t of global step 2048
    __syncthreads();                                   // A reads done; buf reusable

    // phase B staging writes (loads scheduled early by compiler)
    {
        const float4* gq = (const float4*)(Xrow + 10240);
#pragma unroll
        for (int k = 0; k < 5; ++k) bq[tid + TPB * k] = gq[tid + TPB * k];
    }

    // ---- compute phase A ----
#pragma unroll
    for (int i = 0; i < 4; ++i) {
        float tt = f[5 * i + 0];
        float Ii = f[5 * i + 1];
        float Tt = f[5 * i + 2];
        float SS = f[5 * i + 4];
        float tnx = (i < 3) ? f[5 * i + 5] : tnA;
        float dt  = tnx - tt;
        float inv = fast_rcp(Ii);

        v2f t01 = AL01, t23 = AL23;
        float t4 = AL4;
#pragma unroll
        for (int j = 0; j < 10; ++j) {
            float pre = fmaf(SS, W1S[j], fmaf(Tt, W1T[j], BASE[j]));
            float lam = flog2(1.0f + fexp2(pre));
            v2f lam2 = {lam, lam};
            t01 = lam2 * V01[j] + t01;
            t23 = lam2 * V23[j] + t23;
            t4  = fmaf(lam, V4[j], t4);
        }
        oacc = fmaf(-t23.x, inv, oacc);
        if (i == 0) { OCV0 = t23.x; I0 = Ii; T0 = Tt; SOC0 = SS; }

        float g  = dt * t4 * Ii;
        float hh = dt * t01.y;
        v2f sv = {1.f + g, 1.f - hh};
        v2f bv = {g * t23.y, hh * t01.x * Ii};
        v2f iv = {inv, inv};
        cS = iv * a + cS;
        dS = iv * b + dS;
        b  = sv * b + bv;
        a  = sv * a;
    }
    aA = a; bA = b; cA = cS; dA = dS;
    a = (v2f){1.f, 1.f}; b = (v2f){0.f, 0.f};
    cS = (v2f){0.f, 0.f}; dS = (v2f){0.f, 0.f};

    // ================= phase B: steps [2048..4095] =================
    __syncthreads();                                   // stage B visible
#pragma unroll
    for (int j = 0; j < 5; ++j)
        *(float4*)&f[4 * j] = bq[5 * tid + j];
    tnl = buf[20 * ((tid + 1) & (TPB - 1))];
    float tnB = (tid == TPB - 1) ? 0.f : tnl;
    __syncthreads();                                   // B reads done; red alias safe

#pragma unroll
    for (int i = 0; i < 4; ++i) {
        float tt = f[5 * i + 0];
        float Ii = f[5 * i + 1];
        float Tt = f[5 * i + 2];
        float SS = f[5 * i + 4];
        float tnx = (i < 3) ? f[5 * i + 5] : tnB;
        float dt  = tnx - tt;
        float inv = fast_rcp(Ii);

        v2f t01 = AL01, t23 = AL23;
        float t4 = AL4;
#pragma unroll
        for (int j = 0; j < 10; ++j) {
            float pre = fmaf(SS, W1S[j], fmaf(Tt, W1T[j], BASE[j]));
            float lam = flog2(1.0f + fexp2(pre));
            v2f lam2 = {lam, lam};
            t01 = lam2 * V01[j] + t01;
            t23 = lam2 * V23[j] + t23;
            t4  = fmaf(lam, V4[j], t4);
        }
        oacc = fmaf(-t23.x, inv, oacc);

        bool lastl = (tid == TPB - 1) && (i == 3);     // global step 4095: identity
        float g  = lastl ? 0.f : dt * t4 * Ii;
        float hh = lastl ? 0.f : dt * t01.y;
        v2f sv = {1.f + g, 1.f - hh};
        v2f bv = {g * t23.y, hh * t01.x * Ii};
        v2f iv = {inv, inv};
        cS = iv * a + cS;
        dS = iv * b + dS;
        b  = sv * b + bv;
        a  = sv * a;
    }

    // ---- wave reduce: compose A-segments and B-segments (order-preserving) ----
#pragma unroll
    for (int off = 1; off < 64; off <<= 1) {
        v2f a2, b2, c2, d2, a3, b3, c3, d3;
        a2.x = __shfl_down(aA.x, off); a2.y = __shfl_down(aA.y, off);
        b2.x = __shfl_down(bA.x, off); b2.y = __shfl_down(bA.y, off);
        c2.x = __shfl_down(cA.x, off); c2.y = __shfl_down(cA.y, off);
        d2.x = __shfl_down(dA.x, off); d2.y = __shfl_down(dA.y, off);
        a3.x = __shfl_down(a.x, off);  a3.y = __shfl_down(a.y, off);
        b3.x = __shfl_down(b.x, off);  b3.y = __shfl_down(b.y, off);
        c3.x = __shfl_down(cS.x, off); c3.y = __shfl_down(cS.y, off);
        d3.x = __shfl_down(dS.x, off); d3.y = __shfl_down(dS.y, off);
        float o2 = __shfl_down(oacc, off);

        v2f nb = a2 * bA + b2;
        v2f nc = c2 * aA + cA;
        v2f nd = (dA + d2) + c2 * bA;
        aA = a2 * aA; bA = nb; cA = nc; dA = nd;

        nb = a3 * b + b3;
        nc = c3 * a + cS;
        nd = (dS + d3) + c3 * b;
        a = a3 * a; b = nb; cS = nc; dS = nd;

        oacc += o2;
    }

    if (lane == 0) {
        float* rp = red + w * 17;
        rp[0]  = aA.x; rp[1]  = aA.y; rp[2]  = bA.x; rp[3]  = bA.y;
        rp[4]  = cA.x; rp[5]  = cA.y; rp[6]  = dA.x; rp[7]  = dA.y;
        rp[8]  = a.x;  rp[9]  = a.y;  rp[10] = b.x;  rp[11] = b.y;
        rp[12] = cS.x; rp[13] = cS.y; rp[14] = dS.x; rp[15] = dS.y;
        rp[16] = oacc;
    }
    __syncthreads();

    if (tid == 0) {
        v2f Aa, Ab, Ac, Ad, Ba, Bb, Bc, Bd;
        Aa.x = red[0];  Aa.y = red[1];  Ab.x = red[2];  Ab.y = red[3];
        Ac.x = red[4];  Ac.y = red[5];  Ad.x = red[6];  Ad.y = red[7];
        Ba.x = red[8];  Ba.y = red[9];  Bb.x = red[10]; Bb.y = red[11];
        Bc.x = red[12]; Bc.y = red[13]; Bd.x = red[14]; Bd.y = red[15];
        float O = red[16];
#pragma unroll
        for (int k = 1; k < 8; ++k) {
            const float* rp = red + k * 17;
            v2f ak, bk, ck, dk;
            ak.x = rp[0]; ak.y = rp[1]; bk.x = rp[2]; bk.y = rp[3];
            ck.x = rp[4]; ck.y = rp[5]; dk.x = rp[6]; dk.y = rp[7];
            v2f nb = ak * Ab + bk;
            v2f nc = ck * Aa + Ac;
            v2f nd = (Ad + dk) + ck * Ab;
            Aa = ak * Aa; Ab = nb; Ac = nc; Ad = nd;
            ak.x = rp[8];  ak.y = rp[9];  bk.x = rp[10]; bk.y = rp[11];
            ck.x = rp[12]; ck.y = rp[13]; dk.x = rp[14]; dk.y = rp[15];
            nb = ak * Bb + bk;
            nc = ck * Ba + Bc;
            nd = (Bd + dk) + ck * Bb;
            Ba = ak * Ba; Bb = nb; Bc = nc; Bd = nd;
            O += rp[16];
        }
        // total = A then B (only c,d of the product are needed)
        v2f Tc = Bc * Aa + Ac;
        v2f Td = (Ad + Bd) + Bc * Ab;

        // r-net on x[row,0,:] = [SOC0, T0, sc0, sc1, sc2]
        float u = rb1[0];
        u = fmaf(SOC0, rW1[0], u);
        u = fmaf(T0,   rW1[1], u);
        u = fmaf(sc0,  rW1[2], u);
        u = fmaf(sc1,  rW1[3], u);
        u = fmaf(sc2,  rW1[4], u);
        float sp  = LN2 * flog2(1.0f + fexp2(L2E * u));
        float r   = fmaf(sp, rW2[0], rb2[0]);
        float Rs  = sc2 * (1.0f + r);
        float U10 = -OCV0 - I0 * Rs;                   // U_H0 = 0
        float SH  = Td.x;                              // sum U_H/I
        float S1  = fmaf(Tc.y, U10, Td.y);             // sum U_1/I
        out[row]  = (O - SH - S1) * (1.0f / 4096.0f);
    }
}

extern "C" void kernel_launch(void* const* d_in, const int* in_sizes, int n_in,
                              void* d_out, int out_size, void* d_ws, size_t ws_size,
                              hipStream_t stream) {
    const float* X   = (const float*)d_in[0];
    const float* SC  = (const float*)d_in[1];
    const float* pW1 = (const float*)d_in[2];
    const float* pb1 = (const float*)d_in[3];
    const float* pW2 = (const float*)d_in[4];
    const float* pb2 = (const float*)d_in[5];
    const float* rW1 = (const float*)d_in[6];
    const float* rb1 = (const float*)d_in[7];
    const float* rW2 = (const float*)d_in[8];
    const float* rb2 = (const float*)d_in[9];
    float* out = (float*)d_out;

    onenet_fused<<<1024, TPB, 0, stream>>>(X, SC, pW1, pb1, pW2, pb2,
                                           rW1, rb1, rW2, rb2, out);
}

// Round 7
// 140.765 us; speedup vs baseline: 1.0809x; 1.0809x over previous
//
#include <hip/hip_runtime.h>

#define NB   1024
#define NL   4096
#define TPB  256
#define QSTEP 1024               // steps per block (quarter row)
#define SPT  4                   // steps per thread

// ws float-offsets
#define WS_BASE 256              // per-row: BASE[10], Rs at +10, stride 16
#define WS_PART 16640            // partials: [row*4+q]*12, 12 floats each

typedef float v2f __attribute__((ext_vector_type(2)));

__device__ __forceinline__ float fast_rcp(float x) { return __builtin_amdgcn_rcpf(x); }
__device__ __forceinline__ float fexp2(float x) { return __builtin_amdgcn_exp2f(x); }  // 2^x
__device__ __forceinline__ float flog2(float x) { return __builtin_amdgcn_logf(x); }   // log2(x)

#define L2E 1.44269504088896340736f
#define LN2 0.69314718055994530942f

// ---------------- kernel A: weight prep ----------------
__global__ void __launch_bounds__(256) onenet_prep(
    const float* __restrict__ X,   const float* __restrict__ SC,
    const float* __restrict__ pW1, const float* __restrict__ pb1,
    const float* __restrict__ pW2, const float* __restrict__ pb2,
    const float* __restrict__ rW1, const float* __restrict__ rb1,
    const float* __restrict__ rW2, const float* __restrict__ rb2,
    float* __restrict__ ws)
{
    const int gid = blockIdx.x * 256 + threadIdx.x;
    if (gid < NB) {
        float sc0 = SC[gid * 3 + 0], sc1 = SC[gid * 3 + 1], sc2 = SC[gid * 3 + 2];
        float* bp = ws + WS_BASE + gid * 16;
#pragma unroll
        for (int j = 0; j < 10; ++j) {
            float base = fmaf(sc0, pW1[20 + j],
                         fmaf(sc1, pW1[30 + j],
                         fmaf(sc2, pW1[40 + j], pb1[j])));
            bp[j] = L2E * base;
        }
        // r-net on x[:,0,:] = [SOC0, T0, sc0, sc1, sc2]
        const float* x0 = X + (size_t)gid * NL * 5;
        float T0 = x0[2], SOC0 = x0[4];
        float u = rb1[0];
        u = fmaf(SOC0, rW1[0], u);
        u = fmaf(T0,   rW1[1], u);
        u = fmaf(sc0,  rW1[2], u);
        u = fmaf(sc1,  rW1[3], u);
        u = fmaf(sc2,  rW1[4], u);
        float sp = LN2 * flog2(1.0f + fexp2(L2E * u));
        float r  = fmaf(sp, rW2[0], rb2[0]);
        bp[10] = sc2 * (1.0f + r);   // Rs
    }
    // global prescaled weights -> ws[0..74]
    if (blockIdx.x == 0 && threadIdx.x < 75) {
        const int t = threadIdx.x;
        const float LBv[5]   = {0.005f, 0.025f, 0.1f, 0.0f, 0.002f};
        const float UBLB[5]  = {0.015f, 0.045f, 0.9f, 0.055f, 0.023f};
        float v;
        if (t < 20) {
            v = L2E * pW1[t];                       // W1S rows 0..9, W1T rows 10..19
        } else if (t < 70) {
            int k = (t - 20) % 5;
            v = LN2 * 0.0025f * UBLB[k] * pW2[t - 20];   // V[j,k]
        } else {
            int k = t - 70;
            v = LBv[k] + UBLB[k] * fmaf(0.0025f, pb2[k], 0.5f);  // alpha_k
        }
        ws[t] = v;
    }
}

// ---------------- kernel B: main scan-as-reduction ----------------
// block = row*4 + q ; 256 threads x 4 steps = 1024 steps per block.
// Affine (U,S) composition, two systems packed as float2 (.x = U_H, .y = U_1):
//   T_l: U' = a*U + b ; S' = S + (1/I_l)*U  (S-accum uses PRE-step U)
//   theta_k = alpha_k + sum_j log2(1+2^pre_j) * V[j,k]  (sigmoid linearized)
// Global step 4095 gets dt = 0 -> identity transition automatically.
__global__ void __launch_bounds__(TPB) onenet_main(
    const float* __restrict__ X, float* __restrict__ ws)
{
    const int bid  = blockIdx.x;
    const int row  = bid >> 2;
    const int q    = bid & 3;
    const int tid  = threadIdx.x;
    const int lane = tid & 63;
    const int w    = tid >> 6;

    // uniform weights (wave-uniform -> scalar loads)
    float W1S[10], W1T[10], BASE[10], V4[10];
    v2f V01[10], V23[10], AL01, AL23;
    float AL4;
#pragma unroll
    for (int j = 0; j < 10; ++j) W1S[j] = ws[j];
#pragma unroll
    for (int j = 0; j < 10; ++j) W1T[j] = ws[10 + j];
#pragma unroll
    for (int j = 0; j < 10; ++j) {
        V01[j].x = ws[20 + 5 * j + 0];
        V01[j].y = ws[20 + 5 * j + 1];
        V23[j].x = ws[20 + 5 * j + 2];
        V23[j].y = ws[20 + 5 * j + 3];
        V4[j]    = ws[20 + 5 * j + 4];
    }
    AL01.x = ws[70]; AL01.y = ws[71];
    AL23.x = ws[72]; AL23.y = ws[73];
    AL4    = ws[74];
    {
        const float* bp = ws + WS_BASE + row * 16;
#pragma unroll
        for (int j = 0; j < 10; ++j) BASE[j] = bp[j];
    }

    const float* xp = X + ((size_t)row * NL + (size_t)(q * QSTEP + tid * SPT)) * 5;

    float f[20];
#pragma unroll
    for (int k = 0; k < 5; ++k)
        *(float4*)&f[4 * k] = reinterpret_cast<const float4*>(xp)[k];
    // t of the step after this thread's last. For the global last step (q==3,
    // tid==255) use its own t -> dt=0 -> identity (also avoids OOB at row 1023).
    float tn = (q == 3 && tid == TPB - 1) ? f[15] : xp[20];

    v2f a = {1.f, 1.f}, b = {0.f, 0.f}, cS = {0.f, 0.f}, dS = {0.f, 0.f};
    float oacc = 0.f, OCV0 = 0.f, I0 = 0.f;

#pragma unroll
    for (int i = 0; i < SPT; ++i) {
        float tt = f[5 * i + 0];
        float Ii = f[5 * i + 1];
        float Tt = f[5 * i + 2];
        float SS = f[5 * i + 4];
        float tnx = (i < SPT - 1) ? f[5 * i + 5] : tn;
        float dt  = tnx - tt;
        float inv = fast_rcp(Ii);

        v2f t01 = AL01, t23 = AL23;
        float t4 = AL4;
#pragma unroll
        for (int j = 0; j < 10; ++j) {
            float pre = fmaf(SS, W1S[j], fmaf(Tt, W1T[j], BASE[j]));
            float lam = flog2(1.0f + fexp2(pre));
            v2f lam2 = {lam, lam};
            t01 = lam2 * V01[j] + t01;
            t23 = lam2 * V23[j] + t23;
            t4  = fmaf(lam, V4[j], t4);
        }
        // t01.x=R_1, t01.y=RC_r, t23.x=OCV_U, t23.y=M_Hn, t4=K_H
        oacc = fmaf(-t23.x, inv, oacc);
        if (i == 0) { OCV0 = t23.x; I0 = Ii; }

        float g  = dt * t4 * Ii;
        float hh = dt * t01.y;
        v2f sv = {1.f + g, 1.f - hh};
        v2f bv = {g * t23.y, hh * t01.x * Ii};
        v2f iv = {inv, inv};
        cS = iv * a + cS;        // S-accum with pre-step U
        dS = iv * b + dS;
        b  = sv * b + bv;        // then apply T_l
        a  = sv * a;
    }

    // wave-level order-preserving tree reduce (L=self, R=lane+off)
#pragma unroll
    for (int off = 1; off < 64; off <<= 1) {
        v2f a2, b2, c2, d2;
        a2.x = __shfl_down(a.x, off);  a2.y = __shfl_down(a.y, off);
        b2.x = __shfl_down(b.x, off);  b2.y = __shfl_down(b.y, off);
        c2.x = __shfl_down(cS.x, off); c2.y = __shfl_down(cS.y, off);
        d2.x = __shfl_down(dS.x, off); d2.y = __shfl_down(dS.y, off);
        float o2 = __shfl_down(oacc, off);
        v2f nb = a2 * b + b2;
        v2f nc = c2 * a + cS;
        v2f nd = (dS + d2) + c2 * b;
        a = a2 * a; b = nb; cS = nc; dS = nd;
        oacc += o2;
    }

    __shared__ float red[TPB / 64][9];
    if (lane == 0) {
        red[w][0] = a.x;  red[w][1] = a.y;
        red[w][2] = b.x;  red[w][3] = b.y;
        red[w][4] = cS.x; red[w][5] = cS.y;
        red[w][6] = dS.x; red[w][7] = dS.y;
        red[w][8] = oacc;
    }
    __syncthreads();

    if (tid == 0) {
#pragma unroll
        for (int k = 1; k < TPB / 64; ++k) {
            v2f ak, bk, ck, dk;
            ak.x = red[k][0]; ak.y = red[k][1];
            bk.x = red[k][2]; bk.y = red[k][3];
            ck.x = red[k][4]; ck.y = red[k][5];
            dk.x = red[k][6]; dk.y = red[k][7];
            v2f nb = ak * b + bk;
            v2f nc = ck * a + cS;
            v2f nd = (dS + dk) + ck * b;
            a = ak * a; b = nb; cS = nc; dS = nd;
            oacc += red[k][8];
        }
        float* pw = ws + WS_PART + (size_t)bid * 12;
        pw[0] = a.x;  pw[1] = b.x;  pw[2] = cS.x; pw[3] = dS.x;
        pw[4] = a.y;  pw[5] = b.y;  pw[6] = cS.y; pw[7] = dS.y;
        pw[8] = oacc;
        if (q == 0) { pw[9] = OCV0; pw[10] = I0; }
    }
}

// ---------------- kernel C: combine quarters + output ----------------
__global__ void __launch_bounds__(256) onenet_final(
    const float* __restrict__ ws, float* __restrict__ out)
{
    const int row = blockIdx.x * 256 + threadIdx.x;
    if (row >= NB) return;
    const float* p0 = ws + WS_PART + (size_t)row * 48;

    v2f a, b, cS, dS;
    a.x  = p0[0]; a.y  = p0[4];
    b.x  = p0[1]; b.y  = p0[5];
    cS.x = p0[2]; cS.y = p0[6];
    dS.x = p0[3]; dS.y = p0[7];
    float O = p0[8];
    float OCV0 = p0[9], I0 = p0[10];
#pragma unroll
    for (int k = 1; k < 4; ++k) {
        const float* pk = p0 + k * 12;
        v2f ak, bk, ck, dk;
        ak.x = pk[0]; ak.y = pk[4];
        bk.x = pk[1]; bk.y = pk[5];
        ck.x = pk[2]; ck.y = pk[6];
        dk.x = pk[3]; dk.y = pk[7];
        v2f nb = ak * b + bk;
        v2f nc = ck * a + cS;
        v2f nd = (dS + dk) + ck * b;
        a = ak * a; b = nb; cS = nc; dS = nd;
        O += pk[8];
    }
    float Rs  = ws[WS_BASE + row * 16 + 10];
    float U10 = -OCV0 - I0 * Rs;                 // U_H0 = 0
    float SH  = dS.x;                            // sum U_H/I
    float S1  = fmaf(cS.y, U10, dS.y);           // sum U_1/I
    out[row] = (O - SH - S1) * (1.0f / 4096.0f);
}

extern "C" void kernel_launch(void* const* d_in, const int* in_sizes, int n_in,
                              void* d_out, int out_size, void* d_ws, size_t ws_size,
                              hipStream_t stream) {
    const float* X   = (const float*)d_in[0];
    const float* SC  = (const float*)d_in[1];
    const float* pW1 = (const float*)d_in[2];
    const float* pb1 = (const float*)d_in[3];
    const float* pW2 = (const float*)d_in[4];
    const float* pb2 = (const float*)d_in[5];
    const float* rW1 = (const float*)d_in[6];
    const float* rb1 = (const float*)d_in[7];
    const float* rW2 = (const float*)d_in[8];
    const float* rb2 = (const float*)d_in[9];
    float* out = (float*)d_out;
    float* ws  = (float*)d_ws;

    onenet_prep<<<NB / 256, 256, 0, stream>>>(X, SC, pW1, pb1, pW2, pb2,
                                              rW1, rb1, rW2, rb2, ws);
    onenet_main<<<NB * 4, TPB, 0, stream>>>(X, ws);
    onenet_final<<<NB / 256, 256, 0, stream>>>(ws, out);
}